// Round 10
// baseline (56.878 us; speedup 1.0000x reference)
//
#include <hip/hip_runtime.h>

// SingleShotInhibition: out[b,f,hw] = act[b,f,hw] + sum_m filt[m]*act[b,(f+m-13)&511,hw]
// act: [64, 512, 28, 28] fp32, filt: [27] fp32 (center tap == 0 in the data).
//
// R10: LINEAR DRAM streams. R1-R9 all pinned at ~4.0 TB/s regardless of
// width/MLP/occupancy -> the shared trait is the DRAM pattern (1 KB chunks at
// 3136 B stride). Here a block owns (image b, 8-channel chunk); its 34-channel
// window is ONE contiguous ~104 KB span (channels are memory-adjacent).
// Each wave issues 26 address-consecutive 1 KB global_load_lds DMAs -> true
// linear streams (the pattern the 6.3 TB/s copy ceiling was measured on).
// Circular wrap handled by per-lane global addresses (source is per-lane;
// LDS dest stays linear, per m104/m173).
// Halo amp (34/8 = 4.25x) is absorbed by L2 via chunked XCD swizzle:
// XCD x gets images 8x..8x+7; one image (1.57 MB) fits in a 4 MB XCD L2.

typedef float v4f __attribute__((ext_vector_type(4)));

#define SSI_SCOPE 27
#define SSI_HALO  13
#define SSI_C     512
#define SSI_HW    784              // floats per channel row (28*28)
#define SSI_Q     196              // float4 per channel row
#define SSI_CHUNK 8                // output channels per block
#define SSI_WIN   34               // CHUNK + SCOPE - 1 staged channels
#define SSI_WINF  (SSI_WIN * SSI_HW)   // 26656 floats
#define SSI_WINB  (SSI_WINF * 4)       // 106624 bytes (104 KiB + 128 B)
#define SSI_TPB   256
// grid: 64 images x 64 chunks = 4096 blocks (divisible by 8 -> bijective swizzle)

__global__ __launch_bounds__(256) void ssi_kernel(
    const float* __restrict__ act,
    const float* __restrict__ filt,
    float* __restrict__ out)
{
    extern __shared__ float lds[];               // 106624 B dynamic

    // Chunked XCD swizzle: XCD (bid%8) gets 512 consecutive logical tiles.
    const int bid  = (int)blockIdx.x;
    const int sbid = (bid & 7) * 512 + (bid >> 3);
    const int b    = sbid >> 6;                  // image 0..63
    const int k    = sbid & 63;                  // channel chunk 0..63
    const int c0   = k * SSI_CHUNK;
    const int c_lo = (c0 - SSI_HALO + SSI_C) & (SSI_C - 1);

    const int tid  = (int)threadIdx.x;
    const int wv   = tid >> 6;
    const int lane = tid & 63;

    const float* __restrict__ actb = act + (size_t)b * (SSI_C * SSI_HW);

    // ---- stage the flat 34-channel window: 104 x 1KB DMAs + 128 B tail ----
    // Wave wv issues chunks [wv*26, wv*26+26): address-consecutive 1 KB each.
    // Per-lane global address handles the circular seam; LDS dest is linear
    // (wave-uniform base, HW adds lane*16).
#pragma unroll
    for (int i = 0; i < 26; ++i) {
        const int ci  = wv * 26 + i;             // chunk index, wave-uniform
        const int f   = ci * 256 + lane * 4;     // float index in window
        const int ch  = f / SSI_HW;              // window channel (const div)
        const int pos = f - ch * SSI_HW;
        const int c   = (c_lo + ch) & (SSI_C - 1);
        const float* g = actb + c * SSI_HW + pos;
        __builtin_amdgcn_global_load_lds(
            (const __attribute__((address_space(1))) void*)g,
            (__attribute__((address_space(3))) void*)&lds[ci * 256],
            16, 0, 0);
    }
    if (wv == 3 && lane < 8) {                   // 128 B tail (floats 26624..26655)
        const int f   = 104 * 256 + lane * 4;
        const int ch  = f / SSI_HW;
        const int pos = f - ch * SSI_HW;
        const int c   = (c_lo + ch) & (SSI_C - 1);
        const float* g = actb + c * SSI_HW + pos;
        __builtin_amdgcn_global_load_lds(
            (const __attribute__((address_space(1))) void*)g,
            (__attribute__((address_space(3))) void*)&lds[104 * 256],
            16, 0, 0);
    }

    // taps overlap the staging latency (uniform address -> scalar loads)
    float w[SSI_SCOPE];
#pragma unroll
    for (int m = 0; m < SSI_SCOPE; ++m) w[m] = filt[m];

    __syncthreads();                             // drains vmcnt, then barrier

    // ---- compute: 196 threads own one float4 column each ----
    if (tid < SSI_Q) {
        const v4f* __restrict__ ldsv = (const v4f*)lds;

        // Full window into registers once (34 x b128, conflict-free), then
        // every tap of every output comes from regs: LDS read = 1x window.
        v4f v[SSI_WIN];
#pragma unroll
        for (int kk = 0; kk < SSI_WIN; ++kk) v[kk] = ldsv[kk * SSI_Q + tid];

        float* ob = out + (size_t)b * (SSI_C * SSI_HW)
                        + (size_t)c0 * SSI_HW + tid * 4;
#pragma unroll
        for (int dc = 0; dc < SSI_CHUNK; ++dc) {
            v4f acc = v[dc + SSI_HALO];          // residual (center)
#pragma unroll
            for (int m = 0; m < SSI_SCOPE; ++m) {
                if (m == SSI_HALO) continue;     // w[13] == 0 for this input
                const v4f x = v[dc + m];
                acc.x = fmaf(w[m], x.x, acc.x);
                acc.y = fmaf(w[m], x.y, acc.y);
                acc.z = fmaf(w[m], x.z, acc.z);
                acc.w = fmaf(w[m], x.w, acc.w);
            }
            __builtin_nontemporal_store(acc, (v4f*)(ob + dc * SSI_HW));
        }
    }
}

extern "C" void kernel_launch(void* const* d_in, const int* in_sizes, int n_in,
                              void* d_out, int out_size, void* d_ws, size_t ws_size,
                              hipStream_t stream) {
    const float* act  = (const float*)d_in[0];   // 64*512*28*28 fp32
    const float* filt = (const float*)d_in[1];   // 27 fp32
    float* out = (float*)d_out;

    dim3 grid(64 * 64);                          // 4096 blocks
    dim3 block(SSI_TPB);
    hipLaunchKernelGGL(ssi_kernel, grid, block, SSI_WINB, stream, act, filt, out);
}

// Round 11
// 37.900 us; speedup vs baseline: 1.5008x; 1.5008x over previous
//
#include <hip/hip_runtime.h>

// SingleShotInhibition: out[b,f,hw] = act[b,f,hw] + sum_m filt[m]*act[b,(f+m-13)&511,hw]
// act: [64, 512, 28, 28] fp32, filt: [27] fp32 (center tap == 0 in the data).
//
// R11: traffic attack. Empirical law across R1-R10: dur = hbm_bytes / 4.05 TB/s
// (constant BW regardless of width/MLP/occupancy). R10 proved FETCH can drop
// 91 -> 50 MB via ordering (XCD-chunked, window-sharing blocks adjacent), but
// lost the gain to LDS serialization. R11 = R4's register-window structure
// (float4, CHUNK=8, no LDS, no barrier -- known to sit exactly on the 4.05 law)
// with ONLY the block->tile mapping changed to a chunked XCD swizzle:
// same-qtile blocks (64 chunks sharing the full 512-channel span of 4 KB of
// spatial) run consecutively on one XCD -> concurrent set 2 MB < 4 MB L2 ->
// halo amp 4.25x dedups at L2; R4's FETCH 215 MB -> ~1x input or less.

typedef float v4f __attribute__((ext_vector_type(4)));

#define SSI_SCOPE 27
#define SSI_HALO  13
#define SSI_C     512
#define SSI_QPI   196            // float4 quads per image-channel (784/4)
#define SSI_CHUNK 8              // output channels per block
#define SSI_NCHNK 64             // 512 / 8
#define SSI_TPB   256
#define SSI_WIN   (SSI_CHUNK + SSI_SCOPE - 1)   // 34 window channels
// quad columns: 64*196 = 12544 = 49 qtiles * 256 threads
// grid = 49 * 64 = 3136 blocks; 3136 % 8 == 0 -> bijective chunked swizzle

__global__ __launch_bounds__(256) void ssi_kernel(
    const v4f* __restrict__ act,
    const float* __restrict__ filt,
    v4f* __restrict__ out)
{
    // Chunked XCD swizzle: XCD (bid&7) owns 392 consecutive logical tiles.
    // Logical id: chunk-fastest (qtile*64 + chunk) so one qtile's 64
    // chunk-blocks (window-sharing) are time- and XCD-adjacent.
    const int bid   = (int)blockIdx.x;
    const int sbid  = (bid & 7) * 392 + (bid >> 3);
    const int qtile = sbid >> 6;                          // 0..48
    const int ch0   = (sbid & (SSI_NCHNK - 1)) * SSI_CHUNK;

    const int p4 = qtile * SSI_TPB + (int)threadIdx.x;    // < 12544 exactly
    const int b  = p4 / SSI_QPI;
    const int q  = p4 - b * SSI_QPI;

    const v4f* __restrict__ base  = act + (size_t)b * (SSI_C * SSI_QPI) + q;
    v4f* __restrict__       obase = out + (size_t)b * (SSI_C * SSI_QPI) + q;

    // 27 taps, uniform address -> scalar loads / SGPRs.
    float w[SSI_SCOPE];
#pragma unroll
    for (int m = 0; m < SSI_SCOPE; ++m) w[m] = filt[m];

    // 34-channel float4 window in registers (compile-time indices).
    v4f v[SSI_WIN];
#pragma unroll
    for (int k = 0; k < SSI_WIN; ++k) {
        const int c = (ch0 - SSI_HALO + k) & (SSI_C - 1);   // circular wrap
        v[k] = base[c * SSI_QPI];
    }

    // 8 outputs x 26 taps (w[13]==0) x 4 lanes wide, fully unrolled.
#pragma unroll
    for (int j = 0; j < SSI_CHUNK; ++j) {
        v4f acc = v[j + SSI_HALO];                          // residual (center)
#pragma unroll
        for (int m = 0; m < SSI_SCOPE; ++m) {
            if (m == SSI_HALO) continue;                    // w[13] == 0
            const v4f x = v[j + m];
            acc.x = fmaf(w[m], x.x, acc.x);
            acc.y = fmaf(w[m], x.y, acc.y);
            acc.z = fmaf(w[m], x.z, acc.z);
            acc.w = fmaf(w[m], x.w, acc.w);
        }
        __builtin_nontemporal_store(acc, &obase[(ch0 + j) * SSI_QPI]);
    }
}

extern "C" void kernel_launch(void* const* d_in, const int* in_sizes, int n_in,
                              void* d_out, int out_size, void* d_ws, size_t ws_size,
                              hipStream_t stream) {
    const v4f*   act  = (const v4f*)d_in[0];   // 64*512*28*28 fp32, 16B-aligned
    const float* filt = (const float*)d_in[1]; // 27 fp32
    v4f* out = (v4f*)d_out;

    const int qtiles = (64 * SSI_QPI) / SSI_TPB;   // 49
    dim3 grid(qtiles * SSI_NCHNK);                 // 3136 blocks
    dim3 block(SSI_TPB);
    hipLaunchKernelGGL(ssi_kernel, grid, block, 0, stream, act, filt, out);
}